// Round 4
// baseline (930.480 us; speedup 1.0000x reference)
//
#include <hip/hip_runtime.h>
#include <hip/hip_bf16.h>
#include <math.h>

#define HIDC 256
#define LSTR 56   // LDS row stride in ushorts (112 B)

typedef short short8 __attribute__((ext_vector_type(8)));
typedef float f32x4 __attribute__((ext_vector_type(4)));

__device__ __forceinline__ ushort f2bf_rne(float f) {
    uint u = __float_as_uint(f);
    u += 0x7FFF + ((u >> 16) & 1);
    return (ushort)(u >> 16);
}
__device__ __forceinline__ float bf2f(ushort h) {
    return __uint_as_float(((uint)h) << 16);
}

// ---------------- small utility kernels ----------------

__global__ void fill_i_kernel(int* __restrict__ p, int v, int n) {
    int i = blockIdx.x * 256 + threadIdx.x;
    if (i < n) p[i] = v;
}

__global__ void deg_kernel(const int* __restrict__ dst, int* __restrict__ deg, int E) {
    int e = blockIdx.x * 256 + threadIdx.x;
    if (e < E) atomicAdd(&deg[dst[e]], 1);
}

__global__ void rsqrt_kernel(const int* __restrict__ deg, float* __restrict__ dinv, int n) {
    int i = blockIdx.x * 256 + threadIdx.x;
    if (i < n) dinv[i] = rsqrtf((float)(deg[i] + 1));   // +1 = self-loop
}

// ---------------- 3-kernel exclusive scan ----------------

__device__ __forceinline__ int block_incl_scan(int v, int tid) {
#pragma unroll
    for (int off = 1; off < 64; off <<= 1) {
        int t = __shfl_up(v, off);
        if ((tid & 63) >= off) v += t;
    }
    __shared__ int wt[4];
    if ((tid & 63) == 63) wt[tid >> 6] = v;
    __syncthreads();
    int wid = tid >> 6;
    for (int w = 0; w < wid; w++) v += wt[w];
    __syncthreads();
    return v;
}

__global__ void scan_a_kernel(const int* __restrict__ deg, int* __restrict__ row_start,
                              int* __restrict__ blocksum, int N) {
    int tid = threadIdx.x;
    int i = blockIdx.x * 256 + tid;
    int v = (i < N) ? deg[i] : 0;
    int incl = block_incl_scan(v, tid);
    if (i < N) row_start[i + 1] = incl;
    if (tid == 255) blocksum[blockIdx.x] = incl;
}

__global__ void scan_b_kernel(int* __restrict__ blocksum, int nb) {
    int tid = threadIdx.x;
    int v = (tid < nb) ? blocksum[tid] : 0;
    int incl = block_incl_scan(v, tid);
    if (tid < nb) blocksum[tid] = incl;
}

__global__ void scan_c_kernel(int* __restrict__ row_start, int* __restrict__ cursor,
                              const int* __restrict__ blocksum, int N) {
    int b = blockIdx.x;
    int i = b * 256 + threadIdx.x;
    int add = (b > 0) ? blocksum[b - 1] : 0;
    if (i < N) {
        int v = row_start[i + 1] + add;
        row_start[i + 1] = v;
        cursor[i + 1] = v;
    }
    if (b == 0 && threadIdx.x == 0) { row_start[0] = 0; cursor[0] = 0; }
}

// packed CSR: csr_e[pos] = (src, weight-bits)
__global__ void scatter_kernel(const int* __restrict__ src, const int* __restrict__ dst,
                               const float* __restrict__ dinv, int* __restrict__ cursor,
                               int2* __restrict__ csr_e, int E) {
    int e = blockIdx.x * 256 + threadIdx.x;
    if (e < E) {
        int s = src[e], d = dst[e];
        int pos = atomicAdd(&cursor[d], 1);
        csr_e[pos] = make_int2(s, __float_as_int(dinv[s] * dinv[d]));
    }
}

// ---------------- weight prep ----------------

__global__ void prep_bt_kernel(const float* __restrict__ B, ushort* __restrict__ Bt) {
    int n = blockIdx.x, k = threadIdx.x;
    Bt[n * 256 + k] = f2bf_rne(B[k * 256 + n]);
}

// gate weights combined: [256n][512k], rows k<256 <- gWw, k>=256 <- gUw
__global__ void prep_gate_bt_kernel(const float* __restrict__ gWw, const float* __restrict__ gUw,
                                    ushort* __restrict__ Bt) {
    int n = blockIdx.x, k = threadIdx.x;
    Bt[n * 512 + k]       = f2bf_rne(gWw[k * 256 + n]);
    Bt[n * 512 + 256 + k] = f2bf_rne(gUw[k * 256 + n]);
}

// ---------------- MFMA GEMM: C_bf16_slicemajor[M x 256] = A_f32[M x 256] @ B ----------------
// Output layout: C[(n>>5)*N*32 + m*32 + (n&31)]  (8 channel-slices of 32, for XCD-local agg)

__global__ __launch_bounds__(256) void gemm_bf16_kernel(
    const float* __restrict__ A, const ushort* __restrict__ Bt,  // Bt: [256n][256k] bf16
    ushort* __restrict__ C, int M)
{
    __shared__ __align__(16) ushort As[128 * LSTR];
    __shared__ __align__(16) ushort Bs[128 * LSTR];
    const int tl = threadIdx.x;
    const int lane = tl & 63, wave = tl >> 6;
    const int wm = (wave & 1) * 64, wn = (wave >> 1) * 64;
    const int bm = blockIdx.x * 128, bn = blockIdx.y * 128;

    const int ar  = tl >> 1;
    const int akq = (tl & 1) * 16;
    const bool aok = (bm + ar) < M;

    f32x4 acc[4][4] = {};

    for (int k0 = 0; k0 < 256; k0 += 32) {
        {
            const float* ap = A + (size_t)(bm + ar) * HIDC + k0 + akq;
#pragma unroll
            for (int j = 0; j < 4; j++) {
                float4 v = aok ? *(const float4*)(ap + 4 * j) : make_float4(0.f, 0.f, 0.f, 0.f);
                ushort4 h;
                h.x = f2bf_rne(v.x); h.y = f2bf_rne(v.y);
                h.z = f2bf_rne(v.z); h.w = f2bf_rne(v.w);
                *(ushort4*)&As[ar * LSTR + akq + 4 * j] = h;
            }
        }
        {
            const ushort* bp = Bt + (size_t)(bn + ar) * 256 + k0 + akq;
            *(uint4*)&Bs[ar * LSTR + akq]     = *(const uint4*)bp;
            *(uint4*)&Bs[ar * LSTR + akq + 8] = *(const uint4*)(bp + 8);
        }
        __syncthreads();
        const int fr = lane & 15, koff = (lane >> 4) * 8;
        short8 af[4], bfv[4];
#pragma unroll
        for (int t = 0; t < 4; t++) {
            af[t]  = *(const short8*)&As[(wm + t * 16 + fr) * LSTR + koff];
            bfv[t] = *(const short8*)&Bs[(wn + t * 16 + fr) * LSTR + koff];
        }
#pragma unroll
        for (int mt = 0; mt < 4; mt++)
#pragma unroll
            for (int nt = 0; nt < 4; nt++)
                acc[mt][nt] = __builtin_amdgcn_mfma_f32_16x16x32_bf16(af[mt], bfv[nt], acc[mt][nt], 0, 0, 0);
        __syncthreads();
    }

    const int row4 = (lane >> 4) * 4, coln = lane & 15;
    const int Mn = M;  // nodes
#pragma unroll
    for (int mt = 0; mt < 4; mt++)
#pragma unroll
        for (int r = 0; r < 4; r++) {
            int m = bm + wm + mt * 16 + row4 + r;
            if (m < M) {
#pragma unroll
                for (int nt = 0; nt < 4; nt++) {
                    int n = bn + wn + nt * 16 + coln;
                    C[(size_t)(n >> 5) * Mn * 32 + (size_t)m * 32 + (n & 31)] =
                        f2bf_rne(acc[mt][nt][r]);
                }
            }
        }
}

// ---------------- gate GEMM: single-pass bf16, K=512 concat(ht,prev), fused sigmoid blend ----------------

__global__ __launch_bounds__(256) void gate_kernel(
    const float* __restrict__ ht, const float* __restrict__ prev,
    const ushort* __restrict__ Bt,  // [256n][512k]
    const float* __restrict__ gWb, const float* __restrict__ gUb,
    float* __restrict__ out, int M)
{
    __shared__ __align__(16) ushort As[128 * LSTR];
    __shared__ __align__(16) ushort Bs[128 * LSTR];
    const int tl = threadIdx.x;
    const int lane = tl & 63, wave = tl >> 6;
    const int wm = (wave & 1) * 64, wn = (wave >> 1) * 64;
    const int bm = blockIdx.x * 128, bn = blockIdx.y * 128;

    const int ar  = tl >> 1;
    const int akq = (tl & 1) * 16;
    const bool aok = (bm + ar) < M;

    f32x4 acc[4][4] = {};

    for (int k0 = 0; k0 < 512; k0 += 32) {
        {
            const float* srcA = (k0 < 256) ? ht : prev;
            const float* ap = srcA + (size_t)(bm + ar) * HIDC + (k0 & 255) + akq;
#pragma unroll
            for (int j = 0; j < 4; j++) {
                float4 v = aok ? *(const float4*)(ap + 4 * j) : make_float4(0.f, 0.f, 0.f, 0.f);
                ushort4 h;
                h.x = f2bf_rne(v.x); h.y = f2bf_rne(v.y);
                h.z = f2bf_rne(v.z); h.w = f2bf_rne(v.w);
                *(ushort4*)&As[ar * LSTR + akq + 4 * j] = h;
            }
        }
        {
            const ushort* bp = Bt + (size_t)(bn + ar) * 512 + k0 + akq;
            *(uint4*)&Bs[ar * LSTR + akq]     = *(const uint4*)bp;
            *(uint4*)&Bs[ar * LSTR + akq + 8] = *(const uint4*)(bp + 8);
        }
        __syncthreads();
        const int fr = lane & 15, koff = (lane >> 4) * 8;
        short8 af[4], bfv[4];
#pragma unroll
        for (int t = 0; t < 4; t++) {
            af[t]  = *(const short8*)&As[(wm + t * 16 + fr) * LSTR + koff];
            bfv[t] = *(const short8*)&Bs[(wn + t * 16 + fr) * LSTR + koff];
        }
#pragma unroll
        for (int mt = 0; mt < 4; mt++)
#pragma unroll
            for (int nt = 0; nt < 4; nt++)
                acc[mt][nt] = __builtin_amdgcn_mfma_f32_16x16x32_bf16(af[mt], bfv[nt], acc[mt][nt], 0, 0, 0);
        __syncthreads();
    }

    const int row4 = (lane >> 4) * 4, coln = lane & 15;
#pragma unroll
    for (int mt = 0; mt < 4; mt++)
#pragma unroll
        for (int r = 0; r < 4; r++) {
            int m = bm + wm + mt * 16 + row4 + r;
            if (m < M) {
#pragma unroll
                for (int nt = 0; nt < 4; nt++) {
                    int n = bn + wn + nt * 16 + coln;
                    size_t idx = (size_t)m * HIDC + n;
                    float g = acc[mt][nt][r] + gWb[n] + gUb[n];
                    float alpha = 1.f / (1.f + expf(-g));
                    out[idx] = alpha * ht[idx] + (1.f - alpha) * prev[idx];
                }
            }
        }
}

// ---------------- XCD-sliced CSR aggregation ----------------
// hm_s: bf16, slice-major [8][N][32ch]. grid (8, ceil(N/4)), block 256 = 4 waves.
// One wave per node; two edges per iteration (half-wave each, 64-B gather line).
// blockIdx.x = slice -> consecutive blocks hit consecutive XCDs (round-robin heuristic),
// pinning each 3.2 MB slice into one XCD's 4 MB L2.

__global__ __launch_bounds__(256) void csr_agg_sliced_kernel(
    const ushort* __restrict__ hm_s, const int* __restrict__ row_start,
    const int2* __restrict__ csr_e, const float* __restrict__ dinv,
    const float* __restrict__ bias, float* __restrict__ out,
    int N, int do_relu)
{
    const int slice = blockIdx.x;                       // 0..7
    const int node  = blockIdx.y * 4 + (threadIdx.x >> 6);
    const int lane  = threadIdx.x & 63;
    const int half  = lane >> 5;
    const int c     = lane & 31;
    if (node >= N) return;
    const ushort* tab = hm_s + (size_t)slice * N * 32;
    const int b0 = row_start[node], b1 = row_start[node + 1];
    const float di = dinv[node];
    float acc = half ? 0.f : di * di * bf2f(tab[(size_t)node * 32 + c]);
    for (int j = b0 + half; j < b1; j += 2) {
        int2 e = csr_e[j];
        acc += __int_as_float(e.y) * bf2f(tab[(size_t)e.x * 32 + c]);
    }
    acc += __shfl(acc, lane ^ 32);   // combine the two half-wave partial sums
    if (!half) {
        int ch = slice * 32 + c;
        float v = acc + bias[ch];
        if (do_relu) v = fmaxf(v, 0.f);
        out[(size_t)node * HIDC + ch] = v;
    }
}

// ---------------- launch ----------------

extern "C" void kernel_launch(void* const* d_in, const int* in_sizes, int n_in,
                              void* d_out, int out_size, void* d_ws, size_t ws_size,
                              hipStream_t stream) {
    const float* x    = (const float*)d_in[0];
    const int*   ei   = (const int*)d_in[1];
    const float* prev = (const float*)d_in[2];
    const float* W1   = (const float*)d_in[3];
    const float* b1   = (const float*)d_in[4];
    const float* W2   = (const float*)d_in[5];
    const float* b2   = (const float*)d_in[6];
    const float* gWw  = (const float*)d_in[7];
    const float* gWb  = (const float*)d_in[8];
    const float* gUw  = (const float*)d_in[9];
    const float* gUb  = (const float*)d_in[10];

    const int N = in_sizes[0] / HIDC;
    const int E = in_sizes[1] / 2;
    const int* src = ei;
    const int* dst = ei + E;

    float* out  = (float*)d_out;
    float* out1 = out;                       // h_tilde region (scratch: h f32)
    float* ht   = out + (size_t)N * HIDC;    // h_t region (f32)

    float* ws = (float*)d_ws;
    size_t o = 0;
    auto take = [&](size_t n) { size_t r = o; o += (n + 63) & ~(size_t)63; return r; };
    float*  dinv    = ws + take(N);
    int*    degi    = (int*)(ws + take(N));
    int*    row_st  = (int*)(ws + take(N + 1));
    int*    cursor  = (int*)(ws + take(N + 1));
    int2*   csr_e   = (int2*)(ws + take(2 * (size_t)E));
    ushort* Bt1     = (ushort*)(ws + take(256 * 256 / 2));
    ushort* Bt2     = (ushort*)(ws + take(256 * 256 / 2));
    ushort* Btg     = (ushort*)(ws + take(256 * 512 / 2));
    ushort* hm      = (ushort*)(ws + take((size_t)N * HIDC / 2));

    const int nbN = (N + 255) / 256;
    const int nbE = (E + 255) / 256;
    dim3 ggrid((N + 127) / 128, 2);
    dim3 agrid(8, (N + 3) / 4);

    // ---- CSR build ----
    int* blocksum = (int*)csr_e;  // free until scatter_kernel
    fill_i_kernel<<<nbN, 256, 0, stream>>>(degi, 0, N);
    deg_kernel<<<nbE, 256, 0, stream>>>(dst, degi, E);
    scan_a_kernel<<<nbN, 256, 0, stream>>>(degi, row_st, blocksum, N);
    scan_b_kernel<<<1, 256, 0, stream>>>(blocksum, nbN);
    scan_c_kernel<<<nbN, 256, 0, stream>>>(row_st, cursor, blocksum, N);
    rsqrt_kernel<<<nbN, 256, 0, stream>>>(degi, dinv, N);
    scatter_kernel<<<nbE, 256, 0, stream>>>(src, dst, dinv, cursor, csr_e, E);

    // ---- weight prep ----
    prep_bt_kernel<<<256, 256, 0, stream>>>(W1, Bt1);
    prep_bt_kernel<<<256, 256, 0, stream>>>(W2, Bt2);
    prep_gate_bt_kernel<<<256, 256, 0, stream>>>(gWw, gUw, Btg);

    // ---- conv1 ----
    gemm_bf16_kernel<<<ggrid, 256, 0, stream>>>(x, Bt1, hm, N);
    csr_agg_sliced_kernel<<<agrid, 256, 0, stream>>>(hm, row_st, csr_e, dinv, b1, out1, N, 1);

    // ---- conv2 ----
    gemm_bf16_kernel<<<ggrid, 256, 0, stream>>>(out1, Bt2, hm, N);
    csr_agg_sliced_kernel<<<agrid, 256, 0, stream>>>(hm, row_st, csr_e, dinv, b2, ht, N, 0);

    // ---- gate (fused final) ----
    gate_kernel<<<ggrid, 256, 0, stream>>>(ht, prev, Btg, gWb, gUb, out1, N);

    (void)n_in; (void)out_size; (void)ws_size;
}